// Round 2
// baseline (343.974 us; speedup 1.0000x reference)
//
#include <hip/hip_runtime.h>

#define BLOCK 256

typedef float v2f __attribute__((ext_vector_type(2)));

struct WPtrs {
    const float* w[19];
    const float* b[19];
};

enum LId {FU1,FU2,KU1,KU2,HU1,HU2,MD1,MD2,MD3,HD1,HD2,KD1,KD2,HA1,HA2,KA1,KA2,FA1,FA2};

// Each v2f holds the same feature for 2 adjacent rows (.x=row0, .y=row1).
// Weight is a wave-uniform scalar (SGPR) broadcast into both halves of
// v_pk_fma_f32 -> 2 FMAs per instruction per lane.
template<int DIN,int DOUT,bool RELU>
__device__ __forceinline__ void lin(const v2f (&in)[DIN], v2f (&out)[DOUT],
                                    const float* __restrict__ w, const float* __restrict__ b) {
#pragma unroll
    for (int j = 0; j < DOUT; ++j) {
        const float bj = b[j];
        v2f acc = {bj, bj};
#pragma unroll
        for (int i = 0; i < DIN; ++i) {
            const float wij = w[i*DOUT + j];
            v2f wv = {wij, wij};
            acc = __builtin_elementwise_fma(in[i], wv, acc);
        }
        if (RELU) {
            v2f z = {0.0f, 0.0f};
            out[j] = __builtin_elementwise_max(acc, z);
        } else {
            out[j] = acc;
        }
    }
}

__global__ __launch_bounds__(BLOCK) void pnet_kernel(
    const float* __restrict__ x, float* __restrict__ out, int B, WPtrs P) {
    const long long t = (long long)blockIdx.x * BLOCK + threadIdx.x;
    const long long row0 = t * 2;
    if (row0 >= B) return;
    const bool full = (row0 + 2) <= B;

    // ---- load 2 rows x 11 features; transpose to per-feature v2f ----
    v2f xin[11];
    if (full) {
        const v2f* p = (const v2f*)(x + row0 * 11);  // 88*t bytes, 8B aligned
        v2f v[11];
#pragma unroll
        for (int i = 0; i < 11; ++i) v[i] = p[i];
        const float* fv = (const float*)&v[0];
#pragma unroll
        for (int c = 0; c < 11; ++c) { xin[c].x = fv[c]; xin[c].y = fv[11 + c]; }
    } else {
        const float* pr = x + row0 * 11;
#pragma unroll
        for (int c = 0; c < 11; ++c) { xin[c].x = pr[c]; xin[c].y = pr[c]; }
    }

    // ---- f_up: [f, fd] -> 2 -> 2 ----
    v2f fin[2] = {xin[4], xin[10]};
    v2f tf[2], f_up[2];
    lin<2,2,true>(fin, tf, P.w[FU1], P.b[FU1]);
    lin<2,2,true>(tf, f_up, P.w[FU2], P.b[FU2]);

    // ---- k_up: [k, kd, f_up] -> 4 -> 4 ----
    v2f kin[4] = {xin[3], xin[9], f_up[0], f_up[1]};
    v2f tk[4], k_up[4];
    lin<4,4,true>(kin, tk, P.w[KU1], P.b[KU1]);
    lin<4,4,true>(tk, k_up, P.w[KU2], P.b[KU2]);

    // ---- h_up: [h, hd, k_up] -> 6 -> 6 ----
    v2f hin[6] = {xin[2], xin[8], k_up[0], k_up[1], k_up[2], k_up[3]};
    v2f th[6], h_up[6];
    lin<6,6,true>(hin, th, P.w[HU1], P.b[HU1]);
    lin<6,6,true>(th, h_up, P.w[HU2], P.b[HU2]);

    // ---- m_down: [m_obs(5), h_up(6)] -> 16 -> 16 -> 6 ----
    v2f min_[11] = {xin[0], xin[1], xin[5], xin[6], xin[7],
                    h_up[0], h_up[1], h_up[2], h_up[3], h_up[4], h_up[5]};
    v2f t16a[16], t16b[16], m_down[6];
    lin<11,16,true>(min_, t16a, P.w[MD1], P.b[MD1]);
    lin<16,16,true>(t16a, t16b, P.w[MD2], P.b[MD2]);
    lin<16,6,true>(t16b, m_down, P.w[MD3], P.b[MD3]);

    // ---- h_down: m_down -> 4 -> 4 ----
    v2f t4b[4], h_down[4];
    lin<6,4,true>(m_down, t4b, P.w[HD1], P.b[HD1]);
    lin<4,4,true>(t4b, h_down, P.w[HD2], P.b[HD2]);

    // ---- k_down: h_down -> 2 -> 2 ----
    v2f t2b[2], k_down[2];
    lin<4,2,true>(h_down, t2b, P.w[KD1], P.b[KD1]);
    lin<2,2,true>(t2b, k_down, P.w[KD2], P.b[KD2]);

    // ---- h_act: [h, hd, m_down(6)] -> 4 -> 1 (no relu on last) ----
    v2f ha_in[8] = {xin[2], xin[8], m_down[0], m_down[1], m_down[2], m_down[3], m_down[4], m_down[5]};
    v2f t4c[4], h_act[1];
    lin<8,4,true>(ha_in, t4c, P.w[HA1], P.b[HA1]);
    lin<4,1,false>(t4c, h_act, P.w[HA2], P.b[HA2]);

    // ---- k_act: [k, kd, h_down(4)] -> 4 -> 1 ----
    v2f ka_in[6] = {xin[3], xin[9], h_down[0], h_down[1], h_down[2], h_down[3]};
    v2f t4d[4], k_act[1];
    lin<6,4,true>(ka_in, t4d, P.w[KA1], P.b[KA1]);
    lin<4,1,false>(t4d, k_act, P.w[KA2], P.b[KA2]);

    // ---- f_act: [f, fd, k_down(2)] -> 4 -> 1 ----
    v2f fa_in[4] = {xin[4], xin[10], k_down[0], k_down[1]};
    v2f t4e[4], f_act[1];
    lin<4,4,true>(fa_in, t4e, P.w[FA1], P.b[FA1]);
    lin<4,1,false>(t4e, f_act, P.w[FA2], P.b[FA2]);

    // ---- store: per row [h_act, f_act, k_act] ----
    if (full) {
        float ob[6] = {h_act[0].x, f_act[0].x, k_act[0].x,
                       h_act[0].y, f_act[0].y, k_act[0].y};
        v2f* po = (v2f*)(out + row0 * 3);  // 24*row0? -> 48*t bytes... 8B aligned
#pragma unroll
        for (int i = 0; i < 3; ++i) po[i] = ((const v2f*)ob)[i];
    } else {
        out[row0*3+0] = h_act[0].x;
        out[row0*3+1] = f_act[0].x;
        out[row0*3+2] = k_act[0].x;
    }
}

extern "C" void kernel_launch(void* const* d_in, const int* in_sizes, int n_in,
                              void* d_out, int out_size, void* d_ws, size_t ws_size,
                              hipStream_t stream) {
    const float* x = (const float*)d_in[0];
    float* out = (float*)d_out;
    const int B = in_sizes[0] / 11;

    WPtrs P;
    for (int i = 0; i < 19; ++i) {
        P.w[i] = (const float*)d_in[1 + 2*i];
        P.b[i] = (const float*)d_in[2 + 2*i];
    }

    const long long nthreads = ((long long)B + 1) / 2;
    const int blocks = (int)((nthreads + BLOCK - 1) / BLOCK);
    pnet_kernel<<<blocks, BLOCK, 0, stream>>>(x, out, B, P);
}

// Round 3
// 239.764 us; speedup vs baseline: 1.4346x; 1.4346x over previous
//
#include <hip/hip_runtime.h>

#define BLOCK 256
#define R 2

struct WPtrs {
    const float* w[19];
    const float* b[19];
};

enum LId {FU1,FU2,KU1,KU2,HU1,HU2,MD1,MD2,MD3,HD1,HD2,KD1,KD2,HA1,HA2,KA1,KA2,FA1,FA2};

// Scalar FMA with wave-uniform weight -> compiler keeps weight in SGPR and
// emits v_fmac_f32 dst, vgpr_in, sgpr_w : 1 VALU inst per weight per row.
// Bias is materialized into ONE VGPR (vb) shared by both rows' first FMA.
template<int DIN,int DOUT,bool RELU>
__device__ __forceinline__ void lin(const float (&in)[R][DIN], float (&out)[R][DOUT],
                                    const float* __restrict__ w, const float* __restrict__ b) {
#pragma unroll
    for (int j = 0; j < DOUT; ++j) {
        const float w0j = w[j];          // w[0*DOUT + j]
        const float vb  = b[j];          // one v_mov, reused by R rows
        float acc[R];
#pragma unroll
        for (int r = 0; r < R; ++r) acc[r] = __builtin_fmaf(in[r][0], w0j, vb);
#pragma unroll
        for (int i = 1; i < DIN; ++i) {
            const float wij = w[i*DOUT + j];
#pragma unroll
            for (int r = 0; r < R; ++r) acc[r] = __builtin_fmaf(in[r][i], wij, acc[r]);
        }
#pragma unroll
        for (int r = 0; r < R; ++r) out[r][j] = RELU ? fmaxf(acc[r], 0.0f) : acc[r];
    }
}

__global__ __launch_bounds__(BLOCK) void pnet_kernel(
    const float* __restrict__ x, float* __restrict__ out, int B, WPtrs P) {
    const long long t = (long long)blockIdx.x * BLOCK + threadIdx.x;
    const long long row0 = t * R;
    if (row0 >= B) return;
    const bool full = (row0 + R) <= B;

    // ---- load 2 rows x 11 features ----
    float xin[R][11];
    if (full) {
        // 22 consecutive floats, byte offset 88*t (8B aligned) -> 11x dwordx2
        typedef float v2 __attribute__((ext_vector_type(2)));
        const v2* p = (const v2*)(x + row0 * 11);
        v2 v[11];
#pragma unroll
        for (int i = 0; i < 11; ++i) v[i] = p[i];
        const float* fv = (const float*)&v[0];
#pragma unroll
        for (int r = 0; r < R; ++r)
#pragma unroll
            for (int c = 0; c < 11; ++c) xin[r][c] = fv[r*11 + c];
    } else {
#pragma unroll
        for (int r = 0; r < R; ++r) {
            long long row = row0 + r; if (row > (long long)B - 1) row = B - 1;
#pragma unroll
            for (int c = 0; c < 11; ++c) xin[r][c] = x[row*11 + c];
        }
    }

    // ---- f_up: [f, fd] -> 2 -> 2 ----
    float fin[R][2], tf[R][2], f_up[R][2];
#pragma unroll
    for (int r = 0; r < R; ++r) { fin[r][0] = xin[r][4]; fin[r][1] = xin[r][10]; }
    lin<2,2,true>(fin, tf, P.w[FU1], P.b[FU1]);
    lin<2,2,true>(tf, f_up, P.w[FU2], P.b[FU2]);

    // ---- k_up: [k, kd, f_up] -> 4 -> 4 ----
    float kin[R][4], tk[R][4], k_up[R][4];
#pragma unroll
    for (int r = 0; r < R; ++r) {
        kin[r][0] = xin[r][3]; kin[r][1] = xin[r][9];
        kin[r][2] = f_up[r][0]; kin[r][3] = f_up[r][1];
    }
    lin<4,4,true>(kin, tk, P.w[KU1], P.b[KU1]);
    lin<4,4,true>(tk, k_up, P.w[KU2], P.b[KU2]);

    // ---- h_up: [h, hd, k_up] -> 6 -> 6 ----
    float hin[R][6], th[R][6], h_up[R][6];
#pragma unroll
    for (int r = 0; r < R; ++r) {
        hin[r][0] = xin[r][2]; hin[r][1] = xin[r][8];
#pragma unroll
        for (int i = 0; i < 4; ++i) hin[r][2+i] = k_up[r][i];
    }
    lin<6,6,true>(hin, th, P.w[HU1], P.b[HU1]);
    lin<6,6,true>(th, h_up, P.w[HU2], P.b[HU2]);

    // ---- m_down: [m_obs(5), h_up(6)] -> 16 -> 16 -> 6 ----
    float min_[R][11], t16a[R][16], t16b[R][16], m_down[R][6];
#pragma unroll
    for (int r = 0; r < R; ++r) {
        min_[r][0] = xin[r][0]; min_[r][1] = xin[r][1]; min_[r][2] = xin[r][5];
        min_[r][3] = xin[r][6]; min_[r][4] = xin[r][7];
#pragma unroll
        for (int i = 0; i < 6; ++i) min_[r][5+i] = h_up[r][i];
    }
    lin<11,16,true>(min_, t16a, P.w[MD1], P.b[MD1]);
    lin<16,16,true>(t16a, t16b, P.w[MD2], P.b[MD2]);
    lin<16,6,true>(t16b, m_down, P.w[MD3], P.b[MD3]);

    // ---- h_down: m_down -> 4 -> 4 ----
    float t4b[R][4], h_down[R][4];
    lin<6,4,true>(m_down, t4b, P.w[HD1], P.b[HD1]);
    lin<4,4,true>(t4b, h_down, P.w[HD2], P.b[HD2]);

    // ---- k_down: h_down -> 2 -> 2 ----
    float t2b[R][2], k_down[R][2];
    lin<4,2,true>(h_down, t2b, P.w[KD1], P.b[KD1]);
    lin<2,2,true>(t2b, k_down, P.w[KD2], P.b[KD2]);

    // ---- h_act: [h, hd, m_down(6)] -> 4 -> 1 (no relu on last) ----
    float ha_in[R][8], t4c[R][4], h_act[R][1];
#pragma unroll
    for (int r = 0; r < R; ++r) {
        ha_in[r][0] = xin[r][2]; ha_in[r][1] = xin[r][8];
#pragma unroll
        for (int i = 0; i < 6; ++i) ha_in[r][2+i] = m_down[r][i];
    }
    lin<8,4,true>(ha_in, t4c, P.w[HA1], P.b[HA1]);
    lin<4,1,false>(t4c, h_act, P.w[HA2], P.b[HA2]);

    // ---- k_act: [k, kd, h_down(4)] -> 4 -> 1 ----
    float ka_in[R][6], t4d[R][4], k_act[R][1];
#pragma unroll
    for (int r = 0; r < R; ++r) {
        ka_in[r][0] = xin[r][3]; ka_in[r][1] = xin[r][9];
#pragma unroll
        for (int i = 0; i < 4; ++i) ka_in[r][2+i] = h_down[r][i];
    }
    lin<6,4,true>(ka_in, t4d, P.w[KA1], P.b[KA1]);
    lin<4,1,false>(t4d, k_act, P.w[KA2], P.b[KA2]);

    // ---- f_act: [f, fd, k_down(2)] -> 4 -> 1 ----
    float fa_in[R][4], t4e[R][4], f_act[R][1];
#pragma unroll
    for (int r = 0; r < R; ++r) {
        fa_in[r][0] = xin[r][4]; fa_in[r][1] = xin[r][10];
#pragma unroll
        for (int i = 0; i < 2; ++i) fa_in[r][2+i] = k_down[r][i];
    }
    lin<4,4,true>(fa_in, t4e, P.w[FA1], P.b[FA1]);
    lin<4,1,false>(t4e, f_act, P.w[FA2], P.b[FA2]);

    // ---- store: per row [h_act, f_act, k_act] ----
    if (full) {
        // 6 consecutive floats at byte offset 24*row0 = 48*t (8B aligned)
        typedef float v2 __attribute__((ext_vector_type(2)));
        float ob[6] = {h_act[0][0], f_act[0][0], k_act[0][0],
                       h_act[1][0], f_act[1][0], k_act[1][0]};
        v2* po = (v2*)(out + row0 * 3);
#pragma unroll
        for (int i = 0; i < 3; ++i) po[i] = ((const v2*)ob)[i];
    } else {
#pragma unroll
        for (int r = 0; r < R; ++r) {
            long long row = row0 + r;
            if (row < B) {
                out[row*3+0] = h_act[r][0];
                out[row*3+1] = f_act[r][0];
                out[row*3+2] = k_act[r][0];
            }
        }
    }
}

extern "C" void kernel_launch(void* const* d_in, const int* in_sizes, int n_in,
                              void* d_out, int out_size, void* d_ws, size_t ws_size,
                              hipStream_t stream) {
    const float* x = (const float*)d_in[0];
    float* out = (float*)d_out;
    const int B = in_sizes[0] / 11;

    WPtrs P;
    for (int i = 0; i < 19; ++i) {
        P.w[i] = (const float*)d_in[1 + 2*i];
        P.b[i] = (const float*)d_in[2 + 2*i];
    }

    const long long nthreads = ((long long)B + R - 1) / R;
    const int blocks = (int)((nthreads + BLOCK - 1) / BLOCK);
    pnet_kernel<<<blocks, BLOCK, 0, stream>>>(x, out, B, P);
}